// Round 1
// 744.700 us; speedup vs baseline: 1.0236x; 1.0236x over previous
//
#include <hip/hip_runtime.h>
#include <math.h>

// Problem constants
#define B_ 8
#define T_ 64
#define N_ 197
#define D_ 768
#define HIDD_ 3072   // HID*D
#define KF_ 8
#define KT_ 49
#define GSTRIDE 200  // padded row stride of per-pair Gram matrix (doubles)

// Output layout (floats, concatenated in reference return order)
#define Z_SZ    (B_*KF_*KT_*D_)       // 2408448
#define FI_OFF  (Z_SZ)                // 2408448
#define TI_OFF  (FI_OFF + B_*KF_)     // 2408512
#define FM_OFF  (TI_OFF + B_*KF_*KT_) // 2411648
#define TM_OFF  (FM_OFF + B_*T_)      // 2412160
#define TM_SZ   (B_*T_*N_)            // 100864

// Workspace layout (bytes)
#define WS_SCOREP  0                          // 512*24 doubles = 98304
#define WS_FN64    98304                      // 512*768*8 = 3145728
#define WS_H32     (WS_FN64 + 3145728)        // 512*768*4 = 1572864
#define WS_VALID   (WS_H32 + 1572864)         // 512*4 = 2048
#define WS_FIDX    (WS_VALID + 2048)          // 64 ints (pad 256)
#define WS_SIM     (WS_FIDX + 256)            // 8*64*64*8 = 262144
#define WS_G       (WS_SIM + 262144)          // 64*200*200*8 = 20480000
// total ~25.6 MB

// ---------------------------------------------------------------------------
// Kernel A: masked-mean frame_repr (fp64), LayerNorm -> h32, L2-normalized
// fn64, valid flags. One block per (b,t); threads 0..191 own 4 dims (float4).
// ---------------------------------------------------------------------------
__global__ __launch_bounds__(256) void kA(const float* __restrict__ x,
                                          const float* __restrict__ mask,
                                          const float* __restrict__ gamma,
                                          const float* __restrict__ beta,
                                          double* __restrict__ fn64,
                                          float* __restrict__ h32,
                                          int* __restrict__ validw) {
  const int row = blockIdx.x;          // b*T + t
  const int tid = threadIdx.x;
  __shared__ float  ms[N_];
  __shared__ double red[256];
  __shared__ double sh_denom, sh_mu, sh_sd, sh_nrm;
  const float* xr = x + (size_t)row * (N_ * D_);

  if (tid < N_) ms[tid] = mask[(size_t)row * N_ + tid];
  __syncthreads();

  // denom = clip(sum(mask), 1e-6)
  red[tid] = (tid < N_) ? (double)ms[tid] : 0.0;
  __syncthreads();
  for (int s = 128; s > 0; s >>= 1) { if (tid < s) red[tid] += red[tid + s]; __syncthreads(); }
  if (tid == 0) { double d = red[0]; sh_denom = (d > 1e-6) ? d : 1e-6; }
  __syncthreads();
  const double dn = sh_denom;

  // masked mean over n (fp64 accumulate), float4 vector loads
  double a0 = 0.0, a1 = 0.0, a2 = 0.0, a3 = 0.0;
  if (tid < 192) {
    const float* px = xr + tid * 4;
#pragma unroll 4
    for (int n = 0; n < N_; n++) {
      const double mv = (double)ms[n];
      const float4 v = *(const float4*)(px + (size_t)n * D_);
      a0 += (double)v.x * mv;
      a1 += (double)v.y * mv;
      a2 += (double)v.z * mv;
      a3 += (double)v.w * mv;
    }
  }
  const double f0 = a0 / dn, f1 = a1 / dn, f2 = a2 / dn, f3 = a3 / dn;

  // mean
  red[tid] = (tid < 192) ? (f0 + f1 + f2 + f3) : 0.0; __syncthreads();
  for (int s = 128; s > 0; s >>= 1) { if (tid < s) red[tid] += red[tid + s]; __syncthreads(); }
  if (tid == 0) sh_mu = red[0] / (double)D_;
  __syncthreads();
  const double mu = sh_mu;

  // L2 norm (cosine normalize, eps 1e-12)
  red[tid] = (tid < 192) ? (f0 * f0 + f1 * f1 + f2 * f2 + f3 * f3) : 0.0; __syncthreads();
  for (int s = 128; s > 0; s >>= 1) { if (tid < s) red[tid] += red[tid + s]; __syncthreads(); }
  if (tid == 0) { double nr = sqrt(red[0]); sh_nrm = (nr > 1e-12) ? nr : 1e-12; }
  __syncthreads();

  // variance
  red[tid] = (tid < 192) ? ((f0 - mu) * (f0 - mu) + (f1 - mu) * (f1 - mu) +
                            (f2 - mu) * (f2 - mu) + (f3 - mu) * (f3 - mu)) : 0.0;
  __syncthreads();
  for (int s = 128; s > 0; s >>= 1) { if (tid < s) red[tid] += red[tid + s]; __syncthreads(); }
  if (tid == 0) sh_sd = sqrt(red[0] / (double)D_ + 1e-5);
  __syncthreads();
  const double sd = sh_sd, nrm = sh_nrm;

  if (tid < 192) {
    const size_t base = (size_t)row * D_;
    const float4 g  = ((const float4*)gamma)[tid];
    const float4 be = ((const float4*)beta)[tid];
    float4 hv;
    hv.x = (float)((f0 - mu) / sd * (double)g.x + (double)be.x);
    hv.y = (float)((f1 - mu) / sd * (double)g.y + (double)be.y);
    hv.z = (float)((f2 - mu) / sd * (double)g.z + (double)be.z);
    hv.w = (float)((f3 - mu) / sd * (double)g.w + (double)be.w);
    *(float4*)(h32 + base + tid * 4) = hv;
    double2* fp = (double2*)(fn64 + base + tid * 4);
    fp[0] = make_double2(f0 / nrm, f1 / nrm);
    fp[1] = make_double2(f2 / nrm, f3 / nrm);
  }
  if (tid == 0) validw[row] = 1;  // clip(denom,1e-6) > 0 always
}

// ---------------------------------------------------------------------------
// Kernel SB: fused kS (sim = fn.fn^T, fp64, 32 blocks) and kB (score GEMM,
// 384 blocks). The two are independent (both consume only kA outputs, both
// feed kD), so one dispatch lets the small kS ride under kB instead of
// occupying its own serial slot. Shared-LDS union via char buffer.
//   blocks [0,32):  kS body — sim tile (b, 16-row slab)
//   blocks [32,416): kB body — M=512 N=3072 K=768 fp32 GEMM + fp64 epilogue
// ---------------------------------------------------------------------------
__global__ __launch_bounds__(256) void kSB(const double* __restrict__ fn64,
                                           double* __restrict__ simG,
                                           const float* __restrict__ h32,
                                           const float* __restrict__ W1,
                                           const float* __restrict__ b1,
                                           const float* __restrict__ W2,
                                           double* __restrict__ scorep) {
  __shared__ char smem[42496] __attribute__((aligned(16)));
  const int tid = threadIdx.x;

  if (blockIdx.x < 32) {
    // ---- kS: parallel sim = fn.fn^T (fp64), same k-order as before ----
    const int b    = blockIdx.x >> 2;
    const int tile = blockIdx.x & 3;
    const int ty = tid >> 4;          // row within slab (0..15)
    const int tx = tid & 15;          // col group (0..15)
    double* As = (double*)smem;            // [kk][row16+pad] = 64*17 dbl
    double* Bs = (double*)(smem + 8704);   // [kk][col64+pad2] = 64*66 dbl
    double acc[4] = {0.0, 0.0, 0.0, 0.0};

    for (int kc = 0; kc < 12; kc++) {
#pragma unroll
      for (int it = 0; it < 4; it++) {          // A slab: 16x64 dbl
        const int idx = (it << 8) + tid;
        const int row = idx >> 6, kk = idx & 63;
        As[kk * 17 + row] = fn64[((size_t)(b * T_ + tile * 16 + row)) * D_ + kc * 64 + kk];
      }
#pragma unroll
      for (int it = 0; it < 16; it++) {         // B slab: 64x64 dbl
        const int idx = (it << 8) + tid;
        const int row = idx >> 6, kk = idx & 63;
        Bs[kk * 66 + row] = fn64[((size_t)(b * T_ + row)) * D_ + kc * 64 + kk];
      }
      __syncthreads();
#pragma unroll 8
      for (int kk = 0; kk < 64; kk++) {
        const double a = As[kk * 17 + ty];
        const double* bp = Bs + kk * 66 + tx * 4;
        acc[0] += a * bp[0];
        acc[1] += a * bp[1];
        acc[2] += a * bp[2];
        acc[3] += a * bp[3];
      }
      __syncthreads();
    }
    double* o = simG + ((size_t)b * 64 + tile * 16 + ty) * 64 + tx * 4;
    o[0] = acc[0]; o[1] = acc[1]; o[2] = acc[2]; o[3] = acc[3];
  } else {
    // ---- kB: score partials = gelu(h @ W1 + b1) @ W2 per n-block ----
    const int bid2 = blockIdx.x - 32;
    const int nb = bid2 % 24;          // n-block (0..23)
    const int n0 = nb * 128;
    const int m0 = (bid2 / 24) * 32;
    const int tx = tid & 31;   // 32 col-groups of 4
    const int ty = tid >> 5;   // 8 row-groups of 4
    float* As = (float*)smem;            // [k][m], pad 36 -> b128-aligned
    float* Bs = (float*)(smem + 9216);   // [k][n] = 64*128 f32
    float acc[4][4];
#pragma unroll
    for (int r = 0; r < 4; r++)
#pragma unroll
      for (int c = 0; c < 4; c++) acc[r][c] = 0.0f;

    for (int kc = 0; kc < 12; kc++) {
      const int k0 = kc * 64;
#pragma unroll
      for (int it = 0; it < 8; it++) {           // A: 32x64
        int idx = tid + (it << 8);
        int k = idx & 63, m = idx >> 6;
        As[k * 36 + m] = h32[(size_t)(m0 + m) * D_ + k0 + k];
      }
#pragma unroll
      for (int it = 0; it < 8; it++) {           // B: 64x128 float4
        int idx = tid + (it << 8);
        int k = idx >> 5, n4 = idx & 31;
        const float4 v = *(const float4*)(W1 + (size_t)(k0 + k) * HIDD_ + n0 + (n4 << 2));
        *(float4*)(Bs + k * 128 + (n4 << 2)) = v;
      }
      __syncthreads();
#pragma unroll 16
      for (int kk = 0; kk < 64; kk++) {
        float4 av = *(const float4*)(As + kk * 36 + ty * 4);
        float4 bv = *(const float4*)(Bs + kk * 128 + tx * 4);
        const float a[4] = {av.x, av.y, av.z, av.w};
        const float bb[4] = {bv.x, bv.y, bv.z, bv.w};
#pragma unroll
        for (int r = 0; r < 4; r++)
#pragma unroll
          for (int c = 0; c < 4; c++) acc[r][c] += a[r] * bb[c];
      }
      __syncthreads();
    }

    double part[4] = {0.0, 0.0, 0.0, 0.0};
#pragma unroll
    for (int r = 0; r < 4; r++) {
#pragma unroll
      for (int c = 0; c < 4; c++) {
        const int gn = n0 + tx * 4 + c;
        const double v = (double)(acc[r][c] + b1[gn]);
        const double g = 0.5 * v * (1.0 + erf(v * 0.7071067811865475244));
        part[r] += g * (double)W2[gn];
      }
    }
#pragma unroll
    for (int r = 0; r < 4; r++) {
      double s = part[r];
#pragma unroll
      for (int off = 16; off > 0; off >>= 1) s += __shfl_down(s, off, 32);
      if (tx == 0) scorep[(size_t)(m0 + ty * 4 + r) * 24 + nb] = s;
    }
  }
}

// ---------------------------------------------------------------------------
// Kernel D: facility-location greedy. Barrier-free wave-synchronous rewrite:
// 256 threads load sim into LDS (one barrier), then wave 0 alone runs the 8
// greedy steps with shfl-only state (bc, chosen, score all in registers).
// The -sum(bc) term is a candidate-uniform shift -> argmax-invariant ->
// dropped. bc update uses sim[j][tid] (== sim[tid][j] bitwise: Gram of one
// fn set, identical ordered fp64 k-sums) for a coalesced LDS read instead of
// the old same-bank column read.
// ---------------------------------------------------------------------------
__global__ __launch_bounds__(256) void kD(const double* __restrict__ simG,
                                          const double* __restrict__ scorep,
                                          const float* __restrict__ b2,
                                          int* __restrict__ fidxw,
                                          float* __restrict__ out_fidx,
                                          float* __restrict__ out_fmask) {
  const int b = blockIdx.x;
  const int tid = threadIdx.x;
  __shared__ double sim[64 * 64];

  const double2* sp = (const double2*)(simG + (size_t)b * 4096);
#pragma unroll
  for (int it = 0; it < 8; it++) {
    const int idx = (it << 8) + tid;
    ((double2*)sim)[idx] = sp[idx];
  }
  __syncthreads();

  if (tid < 64) {
    // per-lane score (same 24-term summation order as before)
    double s = 0.0;
    const double* pp = scorep + (size_t)(b * T_ + tid) * 24;
    for (int q = 0; q < 24; q++) s += pp[q];
    const double half_score = 0.5 * (s + (double)b2[0]);  // valid always true

    double bc_r = 0.0;
    int chosen_r = 0;

    for (int step = 0; step < KF_; step++) {
      // coverage gain for candidate tid (same ascending-ii fp64 add order)
      double gsum = 0.0;
      for (int ii = 0; ii < 64; ii++) {
        const double bcv = __shfl(bc_r, ii, 64);
        gsum += fmax(bcv, sim[ii * 64 + tid]);
      }
      double tot = gsum + half_score;
      if (chosen_r) tot = -INFINITY;

      // wave argmax, first-max (min index) tie-break == jnp.argmax
      double bv = tot; int bi = tid;
#pragma unroll
      for (int off = 1; off < 64; off <<= 1) {
        const double ov = __shfl_xor(bv, off, 64);
        const int    oi = __shfl_xor(bi, off, 64);
        if (ov > bv || (ov == bv && oi < bi)) { bv = ov; bi = oi; }
      }
      bc_r = fmax(bc_r, sim[bi * 64 + tid]);   // symmetric: == sim[tid][bi]
      if (tid == bi) chosen_r = 1;
      if (tid == 0) {
        fidxw[b * KF_ + step] = bi;
        out_fidx[b * KF_ + step] = (float)bi;
      }
    }
    out_fmask[b * T_ + tid] = chosen_r ? 1.0f : 0.0f;
  }
}

// ---------------------------------------------------------------------------
// Kernel G: per-pair Gram matrix G[i][j] = dot(X_i, X_j), fp64 accumulate.
// LDS stages fp32 (exact input values; cvt->fp64 in regs => bit-identical
// to fp64 staging, half the LDS traffic). Pad 68 -> b128-aligned reads.
// Grid = 64 pairs x 10 symmetric 64x64 tiles; 4x4 consecutive micro-tiles.
// ---------------------------------------------------------------------------
__global__ __launch_bounds__(256) void kG(const float* __restrict__ x,
                                          const int* __restrict__ fidxw,
                                          double* __restrict__ G) {
  static const int TIa[10] = {0,0,0,0,1,1,1,2,2,3};
  static const int TJa[10] = {0,1,2,3,1,2,3,2,3,3};
  const int p  = blockIdx.x / 10;
  const int t  = blockIdx.x - p * 10;
  const int ti = TIa[t], tj = TJa[t];
  const int b  = p >> 3;
  const int fi = fidxw[p];
  const float* X = x + ((size_t)(b * T_ + fi)) * (N_ * D_);
  double* Gp = G + (size_t)p * (GSTRIDE * GSTRIDE);

  __shared__ float As[32 * 68];   // [kk][row64+pad4]
  __shared__ float Bs[32 * 68];
  const int tid = threadIdx.x;
  const int tx = tid & 15;        // col group (x4, consecutive)
  const int ty = tid >> 4;        // row group (x4, consecutive)
  double acc[4][4];
#pragma unroll
  for (int r = 0; r < 4; r++)
#pragma unroll
    for (int c = 0; c < 4; c++) acc[r][c] = 0.0;

  for (int kc = 0; kc < 24; kc++) {
#pragma unroll
    for (int it = 0; it < 2; it++) {
      const int idx = (it << 8) + tid;      // 0..511
      const int row = idx >> 3;             // 0..63
      const int kg  = idx & 7;              // float4 group within 32-k chunk
      const int gra = ti * 64 + row, grb = tj * 64 + row;
      const int ra = (gra < N_) ? gra : (N_ - 1);
      const int rb = (grb < N_) ? grb : (N_ - 1);
      const float4 va = *(const float4*)(X + (size_t)ra * D_ + kc * 32 + kg * 4);
      const float4 vb = *(const float4*)(X + (size_t)rb * D_ + kc * 32 + kg * 4);
      As[(kg * 4 + 0) * 68 + row] = va.x;
      As[(kg * 4 + 1) * 68 + row] = va.y;
      As[(kg * 4 + 2) * 68 + row] = va.z;
      As[(kg * 4 + 3) * 68 + row] = va.w;
      Bs[(kg * 4 + 0) * 68 + row] = vb.x;
      Bs[(kg * 4 + 1) * 68 + row] = vb.y;
      Bs[(kg * 4 + 2) * 68 + row] = vb.z;
      Bs[(kg * 4 + 3) * 68 + row] = vb.w;
    }
    __syncthreads();
#pragma unroll 8
    for (int kk = 0; kk < 32; kk++) {
      const float4 av = *(const float4*)(As + kk * 68 + ty * 4);
      const float4 bv = *(const float4*)(Bs + kk * 68 + tx * 4);
      const double a[4]  = {(double)av.x, (double)av.y, (double)av.z, (double)av.w};
      const double bb[4] = {(double)bv.x, (double)bv.y, (double)bv.z, (double)bv.w};
#pragma unroll
      for (int r = 0; r < 4; r++)
#pragma unroll
        for (int c = 0; c < 4; c++) acc[r][c] += a[r] * bb[c];
    }
    __syncthreads();
  }

#pragma unroll
  for (int r = 0; r < 4; r++) {
    const int gi = ti * 64 + ty * 4 + r;
#pragma unroll
    for (int c = 0; c < 4; c++) {
      const int gj = tj * 64 + tx * 4 + c;
      if (gi < N_ && gj < N_) {
        Gp[(size_t)gi * GSTRIDE + gj] = acc[r][c];
        if (ti != tj) Gp[(size_t)gj * GSTRIDE + gi] = acc[r][c];
      }
    }
  }
}

// ---------------------------------------------------------------------------
// Kernel E2: sequential FPS using precomputed Gram, barrier-free rewrite.
// Wave 0 owns all 256 candidate slots (4 points/lane: pt = lane + 64q,
// q=0..2 always < 197, q=3 guarded). Per step: 4 coalesced G-row segment
// loads + uniform diag load, fp64 dist identical to before, register md,
// shfl_xor butterfly argmax (min-index ties == jnp.argmax). No LDS, no
// __syncthreads in the 48-step loop; waves 1-3 wait at the single barrier
// before the fused epilogue (z gather / token_idx / token_mask).
// ---------------------------------------------------------------------------
__global__ __launch_bounds__(256) void kE2(const double* __restrict__ G,
                                           const float* __restrict__ mask,
                                           const int* __restrict__ fidxw,
                                           const float* __restrict__ x,
                                           float* __restrict__ out) {
  const int p = blockIdx.x;
  const int b = p >> 3;
  const int fi = fidxw[p];
  const double* Gp = G + (size_t)p * (GSTRIDE * GSTRIDE);
  const float* mrow = mask + (size_t)(b * T_ + fi) * N_;
  const float* X = x + ((size_t)(b * T_ + fi)) * (N_ * D_);
  const int tid = threadIdx.x;

  __shared__ int toksS[KT_];

  if (tid < 64) {
    const int l = tid;
    double gd[4]; int vld[4]; double md[4];
#pragma unroll
    for (int q = 0; q < 4; q++) {
      const int pt = l + 64 * q;
      const bool live = pt < N_;
      gd[q] = live ? Gp[(size_t)pt * GSTRIDE + pt] : 0.0;
      vld[q] = (live && (mrow[live ? pt : 0] > 0.5f)) ? 1 : 0;
      md[q] = -INFINITY;
    }

    // step 0: argmax over valid of diag (== argmax of where(valid,|X|^2,-inf))
    double bv = vld[0] ? gd[0] : -INFINITY;
    int bi = l;
#pragma unroll
    for (int q = 1; q < 4; q++) {
      const double v = vld[q] ? gd[q] : -INFINITY;
      if (v > bv) { bv = v; bi = l + 64 * q; }   // ascending pt: ties keep min
    }
#pragma unroll
    for (int off = 1; off < 64; off <<= 1) {
      const double ov = __shfl_xor(bv, off, 64);
      const int    oi = __shfl_xor(bi, off, 64);
      if (ov > bv || (ov == bv && oi < bi)) { bv = ov; bi = oi; }
    }
    int cand = bi;
    if (l == 0) toksS[0] = cand;

    for (int k = 1; k < KT_; k++) {
      const size_t rowbase = (size_t)cand * GSTRIDE;
      const double gdc = Gp[rowbase + cand];           // uniform diag load
      const double g0 = Gp[rowbase + l];
      const double g1 = Gp[rowbase + l + 64];
      const double g2 = Gp[rowbase + l + 128];
      const double d0 = sqrt(fmax(gd[0] + gdc - 2.0 * g0, 0.0));
      const double d1 = sqrt(fmax(gd[1] + gdc - 2.0 * g1, 0.0));
      const double d2 = sqrt(fmax(gd[2] + gdc - 2.0 * g2, 0.0));
      md[0] = vld[0] ? ((k == 1) ? d0 : fmin(md[0], d0)) : -1.0;
      md[1] = vld[1] ? ((k == 1) ? d1 : fmin(md[1], d1)) : -1.0;
      md[2] = vld[2] ? ((k == 1) ? d2 : fmin(md[2], d2)) : -1.0;
      if (l + 192 < N_) {
        const double g3 = Gp[rowbase + l + 192];
        const double d3 = sqrt(fmax(gd[3] + gdc - 2.0 * g3, 0.0));
        md[3] = vld[3] ? ((k == 1) ? d3 : fmin(md[3], d3)) : -1.0;
      }

      bv = md[0]; bi = l;
      if (md[1] > bv) { bv = md[1]; bi = l + 64; }
      if (md[2] > bv) { bv = md[2]; bi = l + 128; }
      if (md[3] > bv) { bv = md[3]; bi = l + 192; }
#pragma unroll
      for (int off = 1; off < 64; off <<= 1) {
        const double ov = __shfl_xor(bv, off, 64);
        const int    oi = __shfl_xor(bi, off, 64);
        if (ov > bv || (ov == bv && oi < bi)) { bv = ov; bi = oi; }
      }
      cand = bi;
      if (l == 0) toksS[k] = cand;
    }
  }
  __syncthreads();

  // fused epilogue: token_idx, token_mask, z gather
  if (tid < KT_) {
    const int tok = toksS[tid];
    out[TI_OFF + p * KT_ + tid] = (float)tok;
    out[TM_OFF + (size_t)(b * T_ + fi) * N_ + tok] = 1.0f;
  }
  if (tid < 192) {
    for (int r = 0; r < KT_; r++) {
      const float4 v = *(const float4*)(X + (size_t)toksS[r] * D_ + tid * 4);
      *(float4*)(out + ((size_t)(p * KT_ + r)) * D_ + tid * 4) = v;
    }
  }
}

// ---------------------------------------------------------------------------
extern "C" void kernel_launch(void* const* d_in, const int* in_sizes, int n_in,
                              void* d_out, int out_size, void* d_ws, size_t ws_size,
                              hipStream_t stream) {
  (void)in_sizes; (void)n_in; (void)ws_size; (void)out_size;
  const float* x     = (const float*)d_in[0];
  const float* mask  = (const float*)d_in[1];
  const float* gamma = (const float*)d_in[2];
  const float* beta  = (const float*)d_in[3];
  const float* W1    = (const float*)d_in[4];
  const float* b1    = (const float*)d_in[5];
  const float* W2    = (const float*)d_in[6];
  const float* b2    = (const float*)d_in[7];
  float* out = (float*)d_out;
  char* ws = (char*)d_ws;

  double* scorep = (double*)(ws + WS_SCOREP);
  double* fn64   = (double*)(ws + WS_FN64);
  float*  h32    = (float*)(ws + WS_H32);
  int*    validw = (int*)(ws + WS_VALID);
  int*    fidxw  = (int*)(ws + WS_FIDX);
  double* simG   = (double*)(ws + WS_SIM);
  double* G      = (double*)(ws + WS_G);

  // zero only the token_mask region (everything else is fully overwritten)
  hipMemsetAsync(out + TM_OFF, 0, (size_t)TM_SZ * sizeof(float), stream);

  kA<<<B_ * T_, 256, 0, stream>>>(x, mask, gamma, beta, fn64, h32, validw);
  kSB<<<32 + (HIDD_ / 128) * ((B_ * T_) / 32), 256, 0, stream>>>(
      fn64, simG, h32, W1, b1, W2, scorep);
  kD<<<B_, 256, 0, stream>>>(simG, scorep, b2, fidxw, out + FI_OFF, out + FM_OFF);
  kG<<<B_ * KF_ * 10, 256, 0, stream>>>(x, fidxw, G);
  kE2<<<B_ * KF_, 256, 0, stream>>>(G, mask, fidxw, x, out);
}